// Round 2
// baseline (380.980 us; speedup 1.0000x reference)
//
#include <hip/hip_runtime.h>
#include <cstdint>

typedef __bf16 bf16x8 __attribute__((ext_vector_type(8)));
typedef float  f32x4  __attribute__((ext_vector_type(4)));
using u16 = unsigned short;

struct alignas(8) u16x4 { u16 x, y, z, w; };

__device__ __forceinline__ u16 f2bf(float f) {
  unsigned u = __builtin_bit_cast(unsigned, f);
  u = (u + 0x7FFFu + ((u >> 16) & 1u)) >> 16;   // RNE; inputs finite
  return (u16)u;
}

#define ASYNC16(gp, lp) __builtin_amdgcn_global_load_lds( \
    (__attribute__((address_space(1))) void*)(void*)(gp),  \
    (__attribute__((address_space(3))) void*)(lp), 16, 0, 0)

// ---------------- ws layout (bytes) ----------------
static constexpr size_t OFF_XBF  = 0;
static constexpr size_t OFF_EW   = 33554432;
static constexpr size_t OFF_U    = 33554432;      // alias: dead before EW written
static constexpr size_t OFF_RW   = 167772160;
static constexpr size_t OFF_PM   = 201326592;
static constexpr size_t OFF_MEAN = 202375168;
static constexpr size_t OFF_G    = 202637312;
static constexpr size_t OFF_RB   = 202641408;
static constexpr size_t OFF_EB   = 202674176;
static constexpr size_t WS_NEED  = 202936320;

// ---------- chunk means (partial over 64 rows) + x -> bf16 conversion ----------
__global__ __launch_bounds__(256) void k_means(const float* __restrict__ x,
                                               float* __restrict__ pm,
                                               u16* __restrict__ xbf) {
  int b = blockIdx.x, q = blockIdx.y, tid = threadIdx.x;
  const float* xb = x + (size_t)b * 262144 + (size_t)q * 65536;
  u16* xo = xbf + (size_t)b * 262144 + (size_t)q * 65536;
  float s0 = 0.f, s1 = 0.f, s2 = 0.f, s3 = 0.f;
  for (int t = 0; t < 64; ++t) {
    const float* row = xb + t * 1024;
    u16* orow = xo + t * 1024;
    float v0 = row[tid], v1 = row[tid + 256], v2 = row[tid + 512], v3 = row[tid + 768];
    s0 += v0; s1 += v1; s2 += v2; s3 += v3;
    orow[tid] = f2bf(v0); orow[tid + 256] = f2bf(v1);
    orow[tid + 512] = f2bf(v2); orow[tid + 768] = f2bf(v3);
  }
  float* p = pm + ((size_t)b * 4 + q) * 1024;
  p[tid] = s0; p[tid + 256] = s1; p[tid + 512] = s2; p[tid + 768] = s3;
}

__global__ __launch_bounds__(256) void k_redmeans(const float* __restrict__ pm,
                                                  float* __restrict__ means) {
  int b = blockIdx.x, tid = threadIdx.x;
  const float* p = pm + (size_t)b * 4096;
  for (int i = tid; i < 1024; i += 256)
    means[b * 1024 + i] = (p[i] + p[1024 + i] + p[2048 + i] + p[3072 + i]) * (1.f / 256.f);
}

// ---------- gating: logits, softmax, loss, rolled g ----------
__global__ __launch_bounds__(512) void k_gate(const float* __restrict__ means,
                                              const float* __restrict__ w_gate,
                                              float* __restrict__ g,
                                              float* __restrict__ loss_out) {
  __shared__ float lg[64][8];
  __shared__ float gates[64][8];
  __shared__ float imp[8];
  int tid = threadIdx.x;
  int b = tid >> 3, e = tid & 7;
  const float* mrow = means + b * 1024;
  float acc = 0.f;
  for (int i = 0; i < 1024; ++i) acc += mrow[i] * w_gate[i * 8 + e];
  lg[b][e] = acc;
  __syncthreads();
  if (tid < 64) {
    float mx = lg[tid][0];
#pragma unroll
    for (int j = 1; j < 8; ++j) mx = fmaxf(mx, lg[tid][j]);
    float s = 0.f, ex[8];
#pragma unroll
    for (int j = 0; j < 8; ++j) { ex[j] = expf(lg[tid][j] - mx); s += ex[j]; }
    float inv = 1.f / s;
#pragma unroll
    for (int j = 0; j < 8; ++j) gates[tid][j] = ex[j] * inv;
  }
  __syncthreads();
  if (tid < 8) {
    float s = 0.f;
    for (int bb = 0; bb < 64; ++bb) s += gates[bb][tid];
    imp[tid] = s;
  }
  __syncthreads();
  if (tid == 0) {
    float mean = 0.f;
#pragma unroll
    for (int j = 0; j < 8; ++j) mean += imp[j];
    mean *= (1.f / 8.f);
    float var = 0.f;
#pragma unroll
    for (int j = 0; j < 8; ++j) { float d = imp[j] - mean; var += d * d; }
    var *= (1.f / 7.f);                           // ddof=1
    // cv^2(load) == 0: load is identically 64 (softmax outputs > 0)
    loss_out[0] = (var / (mean * mean + 1e-10f)) * 1e-5f;
  }
  {
    int r = tid >> 3, ee = tid & 7;
    int src = ((r & 7) == 0) ? r : r - 1;         // roll by one chunk, keep first
    g[r * 8 + ee] = gates[src][ee];
  }
}

// ---------- curve merge pass 1a: U[e][i1][k'*1024+i] = sum_j' C1o[i1][j'] (W-R) ----------
__global__ __launch_bounds__(256) void k_p1a(const float* __restrict__ W,
                                             const float* __restrict__ R,
                                             const float* __restrict__ c1o,
                                             float* __restrict__ U) {
  __shared__ float m[32][32];
  int kp = blockIdx.x, e = blockIdx.y, tid = threadIdx.x;
  for (int idx = tid; idx < 1024; idx += 256) m[idx >> 5][idx & 31] = c1o[e * 1024 + idx];
  __syncthreads();
  for (int q = 0; q < 4; ++q) {
    int i = tid + q * 256;
    float acc[32];
#pragma unroll
    for (int a = 0; a < 32; ++a) acc[a] = 0.f;
    for (int jp = 0; jp < 32; ++jp) {
      size_t off = (size_t)jp * 32768 + (size_t)kp * 1024 + i;
      float v = W[(size_t)e * 1048576 + off] - R[off];
#pragma unroll
      for (int i1 = 0; i1 < 32; ++i1) acc[i1] += m[i1][jp] * v;
    }
#pragma unroll
    for (int i1 = 0; i1 < 32; ++i1)
      U[(size_t)e * 1048576 + (size_t)i1 * 32768 + (size_t)kp * 1024 + i] = acc[i1];
  }
}

// ---------- pass 1b: RW[e][(i1*32+i2)*1024+i] = sum_k' C2o[i2][k'] U[e][i1][k'*1024+i] ----------
__global__ __launch_bounds__(256) void k_p1b(const float* __restrict__ U,
                                             const float* __restrict__ c2o,
                                             float* __restrict__ RW) {
  __shared__ float m[32][32];
  int i1 = blockIdx.x, e = blockIdx.y, tid = threadIdx.x;
  for (int idx = tid; idx < 1024; idx += 256) m[idx >> 5][idx & 31] = c2o[e * 1024 + idx];
  __syncthreads();
  for (int q = 0; q < 4; ++q) {
    int i = tid + q * 256;
    float acc[32];
#pragma unroll
    for (int a = 0; a < 32; ++a) acc[a] = 0.f;
    for (int kp = 0; kp < 32; ++kp) {
      float v = U[(size_t)e * 1048576 + (size_t)i1 * 32768 + (size_t)kp * 1024 + i];
#pragma unroll
      for (int i2 = 0; i2 < 32; ++i2) acc[i2] += m[i2][kp] * v;
    }
#pragma unroll
    for (int i2 = 0; i2 < 32; ++i2)
      RW[(size_t)e * 1048576 + (size_t)(i1 * 32 + i2) * 1024 + i] = acc[i2];
  }
}

// ---------- pass 2 (in-place per row): row <- C2i-mix( C1i-mix(row) ) ----------
__global__ __launch_bounds__(256) void k_p2(float* __restrict__ RW,
                                            const float* __restrict__ c1i,
                                            const float* __restrict__ c2i) {
  __shared__ float rowb[8][1024];
  __shared__ float amat[8][32][33];
  __shared__ float m1[32][32], m2[32][32];
  int blk = blockIdx.x;
  int r0 = blk * 8;
  int e = r0 >> 10;
  int tid = threadIdx.x;
  for (int idx = tid; idx < 1024; idx += 256) {
    m1[idx >> 5][idx & 31] = c1i[e * 1024 + idx];
    m2[idx >> 5][idx & 31] = c2i[e * 1024 + idx];
  }
  for (int idx = tid; idx < 8192; idx += 256) {
    int rr = idx >> 10, cc = idx & 1023;
    rowb[rr][cc] = RW[(size_t)(r0 + rr) * 1024 + cc];
  }
  __syncthreads();
  int grp = tid >> 5, ln = tid & 31;
  // stage A: a[l][m'] = sum_l' C1i[l][l'] row[l'*32+m']   (this thread: m'=ln)
  float aacc[32];
#pragma unroll
  for (int l = 0; l < 32; ++l) aacc[l] = 0.f;
  for (int lp = 0; lp < 32; ++lp) {
    float v = rowb[grp][lp * 32 + ln];
#pragma unroll
    for (int l = 0; l < 32; ++l) aacc[l] += m1[l][lp] * v;
  }
#pragma unroll
  for (int l = 0; l < 32; ++l) amat[grp][l][ln] = aacc[l];
  __syncthreads();
  // stage B: out[l][m] = sum_m' C2i[m][m'] a[l][m']   (this thread: l=ln)
  float bacc[32];
#pragma unroll
  for (int mm = 0; mm < 32; ++mm) bacc[mm] = 0.f;
  for (int mp = 0; mp < 32; ++mp) {
    float v = amat[grp][ln][mp];
#pragma unroll
    for (int mm = 0; mm < 32; ++mm) bacc[mm] += m2[mm][mp] * v;
  }
  float* out = RW + (size_t)(r0 + grp) * 1024 + ln * 32;
#pragma unroll
  for (int mm = 0; mm < 32; ++mm) out[mm] = bacc[mm];
}

// ---------- bias curve merge ----------
// ref: rb1[p][j] = sum_i c1b[p][i] * rb0[i][j]
//      rb [p*32+q] = sum_j c2b[q][j] * rb1[p][j]   (einsum 'bkj,bij->bik')
__global__ __launch_bounds__(256) void k_rb(const float* __restrict__ bias,
                                            const float* __restrict__ res_bias,
                                            const float* __restrict__ c1b,
                                            const float* __restrict__ c2b,
                                            float* __restrict__ rb) {
  __shared__ float rb0[32][33], rb1[32][33], m1[32][32], m2[32][32];
  int e = blockIdx.x, tid = threadIdx.x;
  for (int idx = tid; idx < 1024; idx += 256) {
    int i = idx >> 5, j = idx & 31;
    rb0[i][j] = bias[e * 1024 + idx] - res_bias[idx];
    m1[i][j] = c1b[e * 1024 + idx];
    m2[i][j] = c2b[e * 1024 + idx];
  }
  __syncthreads();
  for (int idx = tid; idx < 1024; idx += 256) {
    int p = idx >> 5, j = idx & 31;
    float s = 0.f;
#pragma unroll
    for (int i = 0; i < 32; ++i) s += m1[p][i] * rb0[i][j];
    rb1[p][j] = s;
  }
  __syncthreads();
  for (int idx = tid; idx < 1024; idx += 256) {
    int p = idx >> 5, q = idx & 31;          // o = p*32 + q; p from rb1 (major), q from c2b (minor)
    float s = 0.f;
#pragma unroll
    for (int j = 0; j < 32; ++j) s += m2[q][j] * rb1[p][j];
    rb[e * 1024 + idx] = s;
  }
}

// ---------- expert bias per chunk ----------
__global__ __launch_bounds__(256) void k_eb(const float* __restrict__ rb,
                                            const float* __restrict__ res_bias,
                                            const float* __restrict__ g,
                                            float* __restrict__ eb) {
  int b = blockIdx.x, tid = threadIdx.x;
  for (int o = tid; o < 1024; o += 256) {
    float a = res_bias[o];
#pragma unroll
    for (int e = 0; e < 8; ++e) a += g[b * 8 + e] * rb[e * 1024 + o];
    eb[b * 1024 + o] = a;
  }
}

// ---------- combine: EW[b][o][i] = bf16( R[o][i] + sum_e g[b][e] RW[e][o][i] ) ----------
__global__ __launch_bounds__(256) void k_combine(const float* __restrict__ RW,
                                                 const float* __restrict__ R,
                                                 const float* __restrict__ g,
                                                 u16* __restrict__ EW) {
  __shared__ float gs[512];
  int o = blockIdx.x, tid = threadIdx.x;
  for (int idx = tid; idx < 512; idx += 256) gs[idx] = g[idx];
  __syncthreads();
  int i0 = tid * 4;
  float4 r4 = *(const float4*)(R + (size_t)o * 1024 + i0);
  float4 w[8];
#pragma unroll
  for (int e = 0; e < 8; ++e)
    w[e] = *(const float4*)(RW + (size_t)e * 1048576 + (size_t)o * 1024 + i0);
  for (int b = 0; b < 64; ++b) {
    float a0 = r4.x, a1 = r4.y, a2 = r4.z, a3 = r4.w;
#pragma unroll
    for (int e = 0; e < 8; ++e) {
      float ge = gs[b * 8 + e];
      a0 += ge * w[e].x; a1 += ge * w[e].y; a2 += ge * w[e].z; a3 += ge * w[e].w;
    }
    u16x4 u; u.x = f2bf(a0); u.y = f2bf(a1); u.z = f2bf(a2); u.w = f2bf(a3);
    *(u16x4*)(EW + (size_t)b * 1048576 + (size_t)o * 1024 + i0) = u;
  }
}

// ---------- main GEMM: y[t][o] = sum_i x[t][i] * EW[b][o][i] + eb[b][o] ----------
__global__ __launch_bounds__(256) void k_gemm(const u16* __restrict__ Xb,
                                              const u16* __restrict__ EW,
                                              const float* __restrict__ eb,
                                              float* __restrict__ Y) {
  __shared__ alignas(16) u16 As[128 * 64];
  __shared__ alignas(16) u16 Bs[128 * 64];
  int blk = blockIdx.x;
  int nt = blk & 7, mt = (blk >> 3) & 1, b = blk >> 4;
  int t0 = b * 256 + mt * 128, o0 = nt * 128;
  int tid = threadIdx.x, lane = tid & 63, w = tid >> 6;
  int wr = w >> 1, wc = w & 1;
  f32x4 acc[4][4] = {};
  const u16* aG = Xb + (size_t)t0 * 1024;
  const u16* bG = EW + (size_t)b * 1048576 + (size_t)o0 * 1024;
  int srow = tid >> 3;
  int scol = (tid & 7) << 3;                        // LDS dest col -> tid*16 bytes (linear, rule #21)
  int gcol = (((tid & 7) ^ ((tid >> 3) & 7)) << 3); // pre-swizzled global source col
  int lr = lane & 15;
  int sx = lr & 7;                                  // row&7 for read-side swizzle
  for (int kt = 0; kt < 16; ++kt) {
    int k0 = kt << 6;
#pragma unroll
    for (int iss = 0; iss < 4; ++iss) {
      int r = srow + iss * 32;
      ASYNC16(aG + (size_t)r * 1024 + k0 + gcol, &As[r * 64 + scol]);
    }
#pragma unroll
    for (int iss = 0; iss < 4; ++iss) {
      int r = srow + iss * 32;
      ASYNC16(bG + (size_t)r * 1024 + k0 + gcol, &Bs[r * 64 + scol]);
    }
    __syncthreads();
#pragma unroll
    for (int kk = 0; kk < 2; ++kk) {
      int c16 = kk * 4 + (lane >> 4);
      int cp = ((c16 ^ sx) << 3);
      bf16x8 af[4], bfr[4];
#pragma unroll
      for (int mi = 0; mi < 4; ++mi)
        af[mi] = *(const bf16x8*)&As[(wr * 64 + mi * 16 + lr) * 64 + cp];
#pragma unroll
      for (int ni = 0; ni < 4; ++ni)
        bfr[ni] = *(const bf16x8*)&Bs[(wc * 64 + ni * 16 + lr) * 64 + cp];
#pragma unroll
      for (int mi = 0; mi < 4; ++mi)
#pragma unroll
        for (int ni = 0; ni < 4; ++ni)
          acc[mi][ni] = __builtin_amdgcn_mfma_f32_16x16x32_bf16(af[mi], bfr[ni], acc[mi][ni], 0, 0, 0);
    }
    __syncthreads();
  }
  int rbase = (lane >> 4) << 2;
#pragma unroll
  for (int ni = 0; ni < 4; ++ni) {
    int o = o0 + wc * 64 + ni * 16 + lr;
    float ebv = eb[b * 1024 + o];
#pragma unroll
    for (int mi = 0; mi < 4; ++mi) {
      int trow = t0 + wr * 64 + mi * 16 + rbase;
      float* yp = Y + (size_t)trow * 1024 + o;
      yp[0]    = acc[mi][ni][0] + ebv;
      yp[1024] = acc[mi][ni][1] + ebv;
      yp[2048] = acc[mi][ni][2] + ebv;
      yp[3072] = acc[mi][ni][3] + ebv;
    }
  }
}

extern "C" void kernel_launch(void* const* d_in, const int* in_sizes, int n_in,
                              void* d_out, int out_size, void* d_ws, size_t ws_size,
                              hipStream_t stream) {
  const float* x      = (const float*)d_in[0];
  const float* w_gate = (const float*)d_in[1];
  const float* weight = (const float*)d_in[2];
  const float* bias   = (const float*)d_in[3];
  const float* res_w  = (const float*)d_in[4];
  const float* res_b  = (const float*)d_in[5];
  const float* c1i    = (const float*)d_in[6];
  const float* c2i    = (const float*)d_in[7];
  const float* c1o    = (const float*)d_in[8];
  const float* c2o    = (const float*)d_in[9];
  const float* c1b    = (const float*)d_in[10];
  const float* c2b    = (const float*)d_in[11];
  float* y = (float*)d_out;

  if (ws_size < WS_NEED) return;

  char* wsb = (char*)d_ws;
  u16*   xbf   = (u16*)(wsb + OFF_XBF);
  u16*   EW    = (u16*)(wsb + OFF_EW);
  float* U     = (float*)(wsb + OFF_U);
  float* RW    = (float*)(wsb + OFF_RW);
  float* pm    = (float*)(wsb + OFF_PM);
  float* means = (float*)(wsb + OFF_MEAN);
  float* g     = (float*)(wsb + OFF_G);
  float* rb    = (float*)(wsb + OFF_RB);
  float* eb    = (float*)(wsb + OFF_EB);

  k_means   <<<dim3(64, 4), 256, 0, stream>>>(x, pm, xbf);
  k_redmeans<<<64, 256, 0, stream>>>(pm, means);
  k_gate    <<<1, 512, 0, stream>>>(means, w_gate, g, y + 16777216);
  k_p1a     <<<dim3(32, 8), 256, 0, stream>>>(weight, res_w, c1o, U);
  k_p1b     <<<dim3(32, 8), 256, 0, stream>>>(U, c2o, RW);
  k_p2      <<<1024, 256, 0, stream>>>(RW, c1i, c2i);
  k_rb      <<<8, 256, 0, stream>>>(bias, res_b, c1b, c2b, rb);
  k_eb      <<<64, 256, 0, stream>>>(rb, res_b, g, eb);
  k_combine <<<1024, 256, 0, stream>>>(RW, res_w, g, EW);
  k_gemm    <<<1024, 256, 0, stream>>>(xbf, EW, eb, y);
}

// Round 3
// 355.761 us; speedup vs baseline: 1.0709x; 1.0709x over previous
//
#include <hip/hip_runtime.h>
#include <cstdint>

typedef __bf16 bf16x8 __attribute__((ext_vector_type(8)));
typedef float  f32x4  __attribute__((ext_vector_type(4)));
using u16 = unsigned short;

struct alignas(8) u16x4 { u16 x, y, z, w; };

__device__ __forceinline__ u16 f2bf(float f) {
  unsigned u = __builtin_bit_cast(unsigned, f);
  u = (u + 0x7FFFu + ((u >> 16) & 1u)) >> 16;   // RNE; inputs finite
  return (u16)u;
}

#define ASYNC16(gp, lp) __builtin_amdgcn_global_load_lds( \
    (__attribute__((address_space(1))) void*)(void*)(gp),  \
    (__attribute__((address_space(3))) void*)(lp), 16, 0, 0)

// ---------------- ws layout (bytes) ----------------
// xbf [16384][1024] bf16 : 32 MB
// EW  [64][1024][1024] bf16 : 128 MB   (T2t aliases first 32 MB; pm aliases next 4 MB —
//                                       both dead before k_combine writes EW)
// RW  [8][1024][1024] f32 : 32 MB
// smalls after RW
static constexpr size_t OFF_XBF  = 0;
static constexpr size_t OFF_EW   = 33554432;
static constexpr size_t OFF_T2   = 33554432;       // alias (mergeA -> mergeB)
static constexpr size_t OFF_PM   = 67108864;       // alias (means -> redmeans), 4 MB
static constexpr size_t OFF_RW   = 167772160;
static constexpr size_t OFF_MEAN = 201326592;
static constexpr size_t OFF_G    = 201588736;
static constexpr size_t OFF_RB   = 201592832;
static constexpr size_t OFF_EB   = 201625600;
static constexpr size_t WS_NEED  = 201887744;

// ---------- chunk means (16-row segments) + x -> bf16 conversion ----------
__global__ __launch_bounds__(256) void k_means(const float* __restrict__ x,
                                               float* __restrict__ pm,
                                               u16* __restrict__ xbf) {
  int b = blockIdx.x, q = blockIdx.y, tid = threadIdx.x;
  const float* xb = x + (size_t)b * 262144 + (size_t)q * 16384;
  u16* xo = xbf + (size_t)b * 262144 + (size_t)q * 16384;
  float s0 = 0.f, s1 = 0.f, s2 = 0.f, s3 = 0.f;
  for (int t = 0; t < 16; ++t) {
    const float* row = xb + t * 1024;
    u16* orow = xo + t * 1024;
    float v0 = row[tid], v1 = row[tid + 256], v2 = row[tid + 512], v3 = row[tid + 768];
    s0 += v0; s1 += v1; s2 += v2; s3 += v3;
    orow[tid] = f2bf(v0); orow[tid + 256] = f2bf(v1);
    orow[tid + 512] = f2bf(v2); orow[tid + 768] = f2bf(v3);
  }
  float* p = pm + ((size_t)b * 16 + q) * 1024;
  p[tid] = s0; p[tid + 256] = s1; p[tid + 512] = s2; p[tid + 768] = s3;
}

__global__ __launch_bounds__(256) void k_redmeans(const float* __restrict__ pm,
                                                  float* __restrict__ means) {
  int b = blockIdx.x, tid = threadIdx.x;
  const float* p = pm + (size_t)b * 16384;
  for (int i = tid; i < 1024; i += 256) {
    float s = 0.f;
#pragma unroll
    for (int q = 0; q < 16; ++q) s += p[q * 1024 + i];
    means[b * 1024 + i] = s * (1.f / 256.f);
  }
}

// ---------- gating: logits, softmax, loss, rolled g ----------
__global__ __launch_bounds__(512) void k_gate(const float* __restrict__ means,
                                              const float* __restrict__ w_gate,
                                              float* __restrict__ g,
                                              float* __restrict__ loss_out) {
  __shared__ float lg[64][8];
  __shared__ float gates[64][8];
  __shared__ float imp[8];
  int tid = threadIdx.x;
  int b = tid >> 3, e = tid & 7;
  const float* mrow = means + b * 1024;
  float a0 = 0.f, a1 = 0.f, a2 = 0.f, a3 = 0.f;
  for (int i = 0; i < 1024; i += 4) {
    float4 mv = *(const float4*)(mrow + i);
    a0 += mv.x * w_gate[i * 8 + e];
    a1 += mv.y * w_gate[(i + 1) * 8 + e];
    a2 += mv.z * w_gate[(i + 2) * 8 + e];
    a3 += mv.w * w_gate[(i + 3) * 8 + e];
  }
  lg[b][e] = (a0 + a1) + (a2 + a3);
  __syncthreads();
  if (tid < 64) {
    float mx = lg[tid][0];
#pragma unroll
    for (int j = 1; j < 8; ++j) mx = fmaxf(mx, lg[tid][j]);
    float s = 0.f, ex[8];
#pragma unroll
    for (int j = 0; j < 8; ++j) { ex[j] = expf(lg[tid][j] - mx); s += ex[j]; }
    float inv = 1.f / s;
#pragma unroll
    for (int j = 0; j < 8; ++j) gates[tid][j] = ex[j] * inv;
  }
  __syncthreads();
  if (tid < 8) {
    float s = 0.f;
    for (int bb = 0; bb < 64; ++bb) s += gates[bb][tid];
    imp[tid] = s;
  }
  __syncthreads();
  if (tid == 0) {
    float mean = 0.f;
#pragma unroll
    for (int j = 0; j < 8; ++j) mean += imp[j];
    mean *= (1.f / 8.f);
    float var = 0.f;
#pragma unroll
    for (int j = 0; j < 8; ++j) { float d = imp[j] - mean; var += d * d; }
    var *= (1.f / 7.f);                           // ddof=1
    loss_out[0] = (var / (mean * mean + 1e-10f)) * 1e-5f;
  }
  {
    int r = tid >> 3, ee = tid & 7;
    int src = ((r & 7) == 0) ? r : r - 1;         // roll by one chunk, keep first
    g[r * 8 + ee] = gates[src][ee];
  }
}

// ---------- mergeA: T2t[e][lm][o] = sum_{j,k} C1o[o1,j] C2o[o2,k] dW[(j,k)][lm] ----------
// block: (c-chunk of 8 lm-columns, e). thread (i1=tid&31, c=tid>>5) holds U[32] in regs.
__global__ __launch_bounds__(256) void k_mergeA(const float* __restrict__ W,
                                                const float* __restrict__ R,
                                                const float* __restrict__ c1o,
                                                const float* __restrict__ c2o,
                                                float* __restrict__ T2t) {
  __shared__ float dw[8 * 1024];        // [c][jk]
  __shared__ float m1[1024], m2[1024];
  int e = blockIdx.y, c0 = blockIdx.x * 8, tid = threadIdx.x;
  const float* We = W + (size_t)e * 1048576;
  for (int idx = tid; idx < 1024; idx += 256) {
    m1[idx] = c1o[e * 1024 + idx];
    m2[idx] = c2o[e * 1024 + idx];
  }
  {
    int r = tid >> 1, h = (tid & 1) * 4;
#pragma unroll
    for (int i = 0; i < 8; ++i) {
      int row = r + i * 128;
      const float4 wv = *(const float4*)(We + (size_t)row * 1024 + c0 + h);
      const float4 rv = *(const float4*)(R + (size_t)row * 1024 + c0 + h);
      dw[(h + 0) * 1024 + row] = wv.x - rv.x;
      dw[(h + 1) * 1024 + row] = wv.y - rv.y;
      dw[(h + 2) * 1024 + row] = wv.z - rv.z;
      dw[(h + 3) * 1024 + row] = wv.w - rv.w;
    }
  }
  __syncthreads();
  int i1 = tid & 31, c = tid >> 5;
  const float* dwc = dw + c * 1024;
  float U[32];
#pragma unroll
  for (int k = 0; k < 32; ++k) U[k] = 0.f;
  for (int j = 0; j < 32; ++j) {
    float cj = m1[i1 * 32 + j];
    const float4* rowp = (const float4*)(dwc + j * 32);
#pragma unroll
    for (int k4 = 0; k4 < 8; ++k4) {
      float4 v = rowp[k4];
      U[k4 * 4 + 0] += cj * v.x; U[k4 * 4 + 1] += cj * v.y;
      U[k4 * 4 + 2] += cj * v.z; U[k4 * 4 + 3] += cj * v.w;
    }
  }
  float* obase = T2t + (size_t)e * 1048576 + (size_t)(c0 + c) * 1024 + i1 * 32;
#pragma unroll
  for (int g4 = 0; g4 < 8; ++g4) {
    float s[4];
#pragma unroll
    for (int q = 0; q < 4; ++q) {
      const float4* m2r = (const float4*)(m2 + (g4 * 4 + q) * 32);
      float acc = 0.f;
#pragma unroll
      for (int k4 = 0; k4 < 8; ++k4) {
        float4 mv = m2r[k4];
        acc += mv.x * U[k4 * 4 + 0] + mv.y * U[k4 * 4 + 1]
             + mv.z * U[k4 * 4 + 2] + mv.w * U[k4 * 4 + 3];
      }
      s[q] = acc;
    }
    float4 o4; o4.x = s[0]; o4.y = s[1]; o4.z = s[2]; o4.w = s[3];
    *(float4*)(obase + g4 * 4) = o4;
  }
}

// ---------- mergeB: RW[e][o][i] = sum_{l,m} C1i[i1,l] C2i[i2,m] T2t[e][(l,m)][o] ----------
__global__ __launch_bounds__(256) void k_mergeB(const float* __restrict__ T2t,
                                                const float* __restrict__ c1i,
                                                const float* __restrict__ c2i,
                                                float* __restrict__ RW) {
  __shared__ float t2[8 * 1024];        // [oc][lm]
  __shared__ float m1[1024], m2[1024];
  int e = blockIdx.y, o0 = blockIdx.x * 8, tid = threadIdx.x;
  const float* Te = T2t + (size_t)e * 1048576;
  for (int idx = tid; idx < 1024; idx += 256) {
    m1[idx] = c1i[e * 1024 + idx];
    m2[idx] = c2i[e * 1024 + idx];
  }
  {
    int r = tid >> 1, h = (tid & 1) * 4;
#pragma unroll
    for (int i = 0; i < 8; ++i) {
      int row = r + i * 128;
      const float4 tv = *(const float4*)(Te + (size_t)row * 1024 + o0 + h);
      t2[(h + 0) * 1024 + row] = tv.x;
      t2[(h + 1) * 1024 + row] = tv.y;
      t2[(h + 2) * 1024 + row] = tv.z;
      t2[(h + 3) * 1024 + row] = tv.w;
    }
  }
  __syncthreads();
  int i1 = tid & 31, oc = tid >> 5;
  const float* t2c = t2 + oc * 1024;
  float A[32];
#pragma unroll
  for (int m = 0; m < 32; ++m) A[m] = 0.f;
  for (int l = 0; l < 32; ++l) {
    float cl = m1[i1 * 32 + l];
    const float4* rowp = (const float4*)(t2c + l * 32);
#pragma unroll
    for (int m4 = 0; m4 < 8; ++m4) {
      float4 v = rowp[m4];
      A[m4 * 4 + 0] += cl * v.x; A[m4 * 4 + 1] += cl * v.y;
      A[m4 * 4 + 2] += cl * v.z; A[m4 * 4 + 3] += cl * v.w;
    }
  }
  float* obase = RW + ((size_t)e * 1024 + o0 + oc) * 1024 + i1 * 32;
#pragma unroll
  for (int g4 = 0; g4 < 8; ++g4) {
    float s[4];
#pragma unroll
    for (int q = 0; q < 4; ++q) {
      const float4* m2r = (const float4*)(m2 + (g4 * 4 + q) * 32);
      float acc = 0.f;
#pragma unroll
      for (int m4 = 0; m4 < 8; ++m4) {
        float4 mv = m2r[m4];
        acc += mv.x * A[m4 * 4 + 0] + mv.y * A[m4 * 4 + 1]
             + mv.z * A[m4 * 4 + 2] + mv.w * A[m4 * 4 + 3];
      }
      s[q] = acc;
    }
    float4 o4; o4.x = s[0]; o4.y = s[1]; o4.z = s[2]; o4.w = s[3];
    *(float4*)(obase + g4 * 4) = o4;
  }
}

// ---------- bias curve merge ----------
__global__ __launch_bounds__(256) void k_rb(const float* __restrict__ bias,
                                            const float* __restrict__ res_bias,
                                            const float* __restrict__ c1b,
                                            const float* __restrict__ c2b,
                                            float* __restrict__ rb) {
  __shared__ float rb0[32][33], rb1[32][33], m1[32][32], m2[32][32];
  int e = blockIdx.x, tid = threadIdx.x;
  for (int idx = tid; idx < 1024; idx += 256) {
    int i = idx >> 5, j = idx & 31;
    rb0[i][j] = bias[e * 1024 + idx] - res_bias[idx];
    m1[i][j] = c1b[e * 1024 + idx];
    m2[i][j] = c2b[e * 1024 + idx];
  }
  __syncthreads();
  for (int idx = tid; idx < 1024; idx += 256) {
    int p = idx >> 5, j = idx & 31;
    float s = 0.f;
#pragma unroll
    for (int i = 0; i < 32; ++i) s += m1[p][i] * rb0[i][j];
    rb1[p][j] = s;
  }
  __syncthreads();
  for (int idx = tid; idx < 1024; idx += 256) {
    int p = idx >> 5, q = idx & 31;
    float s = 0.f;
#pragma unroll
    for (int j = 0; j < 32; ++j) s += m2[q][j] * rb1[p][j];
    rb[e * 1024 + idx] = s;
  }
}

// ---------- expert bias per chunk ----------
__global__ __launch_bounds__(256) void k_eb(const float* __restrict__ rb,
                                            const float* __restrict__ res_bias,
                                            const float* __restrict__ g,
                                            float* __restrict__ eb) {
  int b = blockIdx.x, tid = threadIdx.x;
  for (int o = tid; o < 1024; o += 256) {
    float a = res_bias[o];
#pragma unroll
    for (int e = 0; e < 8; ++e) a += g[b * 8 + e] * rb[e * 1024 + o];
    eb[b * 1024 + o] = a;
  }
}

// ---------- combine: EW[b][o][i] = bf16( R[o][i] + sum_e g[b][e] RW[e][o][i] ) ----------
__global__ __launch_bounds__(256) void k_combine(const float* __restrict__ RW,
                                                 const float* __restrict__ R,
                                                 const float* __restrict__ g,
                                                 u16* __restrict__ EW) {
  __shared__ float gs[512];
  int o = blockIdx.x, tid = threadIdx.x;
  for (int idx = tid; idx < 512; idx += 256) gs[idx] = g[idx];
  __syncthreads();
  int i0 = tid * 4;
  float4 r4 = *(const float4*)(R + (size_t)o * 1024 + i0);
  float4 w[8];
#pragma unroll
  for (int e = 0; e < 8; ++e)
    w[e] = *(const float4*)(RW + (size_t)e * 1048576 + (size_t)o * 1024 + i0);
  for (int b = 0; b < 64; ++b) {
    float a0 = r4.x, a1 = r4.y, a2 = r4.z, a3 = r4.w;
#pragma unroll
    for (int e = 0; e < 8; ++e) {
      float ge = gs[b * 8 + e];
      a0 += ge * w[e].x; a1 += ge * w[e].y; a2 += ge * w[e].z; a3 += ge * w[e].w;
    }
    u16x4 u; u.x = f2bf(a0); u.y = f2bf(a1); u.z = f2bf(a2); u.w = f2bf(a3);
    *(u16x4*)(EW + (size_t)b * 1048576 + (size_t)o * 1024 + i0) = u;
  }
}

// ---------- main GEMM: y[t][o] = sum_i x[t][i] * EW[b][o][i] + eb[b][o] ----------
__global__ __launch_bounds__(256) void k_gemm(const u16* __restrict__ Xb,
                                              const u16* __restrict__ EW,
                                              const float* __restrict__ eb,
                                              float* __restrict__ Y) {
  __shared__ alignas(16) u16 As[128 * 64];
  __shared__ alignas(16) u16 Bs[128 * 64];
  int blk = blockIdx.x;
  int nt = blk & 7, mt = (blk >> 3) & 1, b = blk >> 4;
  int t0 = b * 256 + mt * 128, o0 = nt * 128;
  int tid = threadIdx.x, lane = tid & 63, w = tid >> 6;
  int wr = w >> 1, wc = w & 1;
  f32x4 acc[4][4] = {};
  const u16* aG = Xb + (size_t)t0 * 1024;
  const u16* bG = EW + (size_t)b * 1048576 + (size_t)o0 * 1024;
  int srow = tid >> 3;
  int scol = (tid & 7) << 3;
  int gcol = (((tid & 7) ^ ((tid >> 3) & 7)) << 3);
  int lr = lane & 15;
  int sx = lr & 7;
  for (int kt = 0; kt < 16; ++kt) {
    int k0 = kt << 6;
#pragma unroll
    for (int iss = 0; iss < 4; ++iss) {
      int r = srow + iss * 32;
      ASYNC16(aG + (size_t)r * 1024 + k0 + gcol, &As[r * 64 + scol]);
    }
#pragma unroll
    for (int iss = 0; iss < 4; ++iss) {
      int r = srow + iss * 32;
      ASYNC16(bG + (size_t)r * 1024 + k0 + gcol, &Bs[r * 64 + scol]);
    }
    __syncthreads();
#pragma unroll
    for (int kk = 0; kk < 2; ++kk) {
      int c16 = kk * 4 + (lane >> 4);
      int cp = ((c16 ^ sx) << 3);
      bf16x8 af[4], bfr[4];
#pragma unroll
      for (int mi = 0; mi < 4; ++mi)
        af[mi] = *(const bf16x8*)&As[(wr * 64 + mi * 16 + lr) * 64 + cp];
#pragma unroll
      for (int ni = 0; ni < 4; ++ni)
        bfr[ni] = *(const bf16x8*)&Bs[(wc * 64 + ni * 16 + lr) * 64 + cp];
#pragma unroll
      for (int mi = 0; mi < 4; ++mi)
#pragma unroll
        for (int ni = 0; ni < 4; ++ni)
          acc[mi][ni] = __builtin_amdgcn_mfma_f32_16x16x32_bf16(af[mi], bfr[ni], acc[mi][ni], 0, 0, 0);
    }
    __syncthreads();
  }
  int rbase = (lane >> 4) << 2;
#pragma unroll
  for (int ni = 0; ni < 4; ++ni) {
    int o = o0 + wc * 64 + ni * 16 + lr;
    float ebv = eb[b * 1024 + o];
#pragma unroll
    for (int mi = 0; mi < 4; ++mi) {
      int trow = t0 + wr * 64 + mi * 16 + rbase;
      float* yp = Y + (size_t)trow * 1024 + o;
      yp[0]    = acc[mi][ni][0] + ebv;
      yp[1024] = acc[mi][ni][1] + ebv;
      yp[2048] = acc[mi][ni][2] + ebv;
      yp[3072] = acc[mi][ni][3] + ebv;
    }
  }
}

extern "C" void kernel_launch(void* const* d_in, const int* in_sizes, int n_in,
                              void* d_out, int out_size, void* d_ws, size_t ws_size,
                              hipStream_t stream) {
  const float* x      = (const float*)d_in[0];
  const float* w_gate = (const float*)d_in[1];
  const float* weight = (const float*)d_in[2];
  const float* bias   = (const float*)d_in[3];
  const float* res_w  = (const float*)d_in[4];
  const float* res_b  = (const float*)d_in[5];
  const float* c1i    = (const float*)d_in[6];
  const float* c2i    = (const float*)d_in[7];
  const float* c1o    = (const float*)d_in[8];
  const float* c2o    = (const float*)d_in[9];
  const float* c1b    = (const float*)d_in[10];
  const float* c2b    = (const float*)d_in[11];
  float* y = (float*)d_out;

  if (ws_size < WS_NEED) return;

  char* wsb = (char*)d_ws;
  u16*   xbf   = (u16*)(wsb + OFF_XBF);
  u16*   EW    = (u16*)(wsb + OFF_EW);
  float* T2t   = (float*)(wsb + OFF_T2);
  float* pm    = (float*)(wsb + OFF_PM);
  float* RW    = (float*)(wsb + OFF_RW);
  float* means = (float*)(wsb + OFF_MEAN);
  float* g     = (float*)(wsb + OFF_G);
  float* rb    = (float*)(wsb + OFF_RB);
  float* eb    = (float*)(wsb + OFF_EB);

  k_means   <<<dim3(64, 16), 256, 0, stream>>>(x, pm, xbf);
  k_redmeans<<<64, 256, 0, stream>>>(pm, means);
  k_gate    <<<1, 512, 0, stream>>>(means, w_gate, g, y + 16777216);
  k_mergeA  <<<dim3(128, 8), 256, 0, stream>>>(weight, res_w, c1o, c2o, T2t);
  k_mergeB  <<<dim3(128, 8), 256, 0, stream>>>(T2t, c1i, c2i, RW);
  k_rb      <<<8, 256, 0, stream>>>(bias, res_b, c1b, c2b, rb);
  k_eb      <<<64, 256, 0, stream>>>(rb, res_b, g, eb);
  k_combine <<<1024, 256, 0, stream>>>(RW, res_w, g, EW);
  k_gemm    <<<1024, 256, 0, stream>>>(xbf, EW, eb, y);
}

// Round 4
// 258.990 us; speedup vs baseline: 1.4710x; 1.3736x over previous
//
#include <hip/hip_runtime.h>
#include <cstdint>

typedef __bf16 bf16x8 __attribute__((ext_vector_type(8)));
typedef float  f32x4  __attribute__((ext_vector_type(4)));
using u16 = unsigned short;

struct alignas(8) u16x4 { u16 x, y, z, w; };

__device__ __forceinline__ u16 f2bf(float f) {
  unsigned u = __builtin_bit_cast(unsigned, f);
  u = (u + 0x7FFFu + ((u >> 16) & 1u)) >> 16;   // RNE; inputs finite
  return (u16)u;
}

#define ASYNC16(gp, lp) __builtin_amdgcn_global_load_lds( \
    (__attribute__((address_space(1))) void*)(void*)(gp),  \
    (__attribute__((address_space(3))) void*)(lp), 16, 0, 0)

// ---------------- ws layout (bytes) ----------------
static constexpr size_t OFF_XBF  = 0;
static constexpr size_t OFF_EW   = 33554432;
static constexpr size_t OFF_T2   = 33554432;       // alias (mergeA -> mergeB)
static constexpr size_t OFF_PM   = 67108864;       // alias (means partials), 4 MB
static constexpr size_t OFF_RW   = 167772160;
static constexpr size_t OFF_LG   = 201326592;      // logits [64][8]
static constexpr size_t OFF_G    = 201588736;
static constexpr size_t OFF_RB   = 201592832;
static constexpr size_t OFF_EB   = 201625600;
static constexpr size_t WS_NEED  = 201887744;

// ---------- chunk means (16-row segments) + x -> bf16 conversion ----------
__global__ __launch_bounds__(256) void k_means(const float* __restrict__ x,
                                               float* __restrict__ pm,
                                               u16* __restrict__ xbf) {
  int b = blockIdx.x, q = blockIdx.y, tid = threadIdx.x;
  const float* xb = x + (size_t)b * 262144 + (size_t)q * 16384;
  u16* xo = xbf + (size_t)b * 262144 + (size_t)q * 16384;
  float s0 = 0.f, s1 = 0.f, s2 = 0.f, s3 = 0.f;
  for (int t = 0; t < 16; ++t) {
    const float* row = xb + t * 1024;
    u16* orow = xo + t * 1024;
    float v0 = row[tid], v1 = row[tid + 256], v2 = row[tid + 512], v3 = row[tid + 768];
    s0 += v0; s1 += v1; s2 += v2; s3 += v3;
    orow[tid] = f2bf(v0); orow[tid + 256] = f2bf(v1);
    orow[tid + 512] = f2bf(v2); orow[tid + 768] = f2bf(v3);
  }
  float* p = pm + ((size_t)b * 16 + q) * 1024;
  p[tid] = s0; p[tid + 256] = s1; p[tid + 512] = s2; p[tid + 768] = s3;
}

// ---------- reduce partial means + logits GEMV (fused) ----------
// block b: logits[b][e] = (1/256) * sum_i (sum_q pm[b][q][i]) * w_gate[i][e]
__global__ __launch_bounds__(256) void k_redlogits(const float* __restrict__ pm,
                                                   const float* __restrict__ w_gate,
                                                   float* __restrict__ logits) {
  __shared__ float red[4][8];
  int b = blockIdx.x, tid = threadIdx.x;
  const float* p = pm + (size_t)b * 16384 + tid * 4;
  float4 s = {0.f, 0.f, 0.f, 0.f};
#pragma unroll
  for (int q = 0; q < 16; ++q) {
    float4 v = *(const float4*)(p + q * 1024);
    s.x += v.x; s.y += v.y; s.z += v.z; s.w += v.w;
  }
  int i0 = tid * 4;
  float acc[8];
#pragma unroll
  for (int e = 0; e < 8; ++e) {
    acc[e] = s.x * w_gate[(i0 + 0) * 8 + e] + s.y * w_gate[(i0 + 1) * 8 + e]
           + s.z * w_gate[(i0 + 2) * 8 + e] + s.w * w_gate[(i0 + 3) * 8 + e];
  }
#pragma unroll
  for (int off = 32; off >= 1; off >>= 1)
#pragma unroll
    for (int e = 0; e < 8; ++e) acc[e] += __shfl_down(acc[e], off, 64);
  int wv = tid >> 6;
  if ((tid & 63) == 0)
#pragma unroll
    for (int e = 0; e < 8; ++e) red[wv][e] = acc[e];
  __syncthreads();
  if (tid < 8)
    logits[b * 8 + tid] =
        (red[0][tid] + red[1][tid] + red[2][tid] + red[3][tid]) * (1.f / 256.f);
}

// ---------- softmax + loss + roll (tiny, 1 wave) ----------
__global__ __launch_bounds__(64) void k_gatefin(const float* __restrict__ logits,
                                                float* __restrict__ g,
                                                float* __restrict__ loss_out) {
  __shared__ float gates[64][8];
  __shared__ float imp[8];
  int b = threadIdx.x;
  {
    float lg[8];
#pragma unroll
    for (int j = 0; j < 8; ++j) lg[j] = logits[b * 8 + j];
    float mx = lg[0];
#pragma unroll
    for (int j = 1; j < 8; ++j) mx = fmaxf(mx, lg[j]);
    float s = 0.f, ex[8];
#pragma unroll
    for (int j = 0; j < 8; ++j) { ex[j] = expf(lg[j] - mx); s += ex[j]; }
    float inv = 1.f / s;
#pragma unroll
    for (int j = 0; j < 8; ++j) gates[b][j] = ex[j] * inv;
  }
  __syncthreads();
  if (b < 8) {
    float s = 0.f;
    for (int bb = 0; bb < 64; ++bb) s += gates[bb][b];
    imp[b] = s;
  }
  __syncthreads();
  if (b == 0) {
    float mean = 0.f;
#pragma unroll
    for (int j = 0; j < 8; ++j) mean += imp[j];
    mean *= (1.f / 8.f);
    float var = 0.f;
#pragma unroll
    for (int j = 0; j < 8; ++j) { float d = imp[j] - mean; var += d * d; }
    var *= (1.f / 7.f);                           // ddof=1
    // cv^2(load) == 0: load is identically 64 (softmax outputs > 0)
    loss_out[0] = (var / (mean * mean + 1e-10f)) * 1e-5f;
  }
  __syncthreads();
  {
    int src = ((b & 7) == 0) ? b : b - 1;         // roll by one chunk, keep first
#pragma unroll
    for (int j = 0; j < 8; ++j) g[b * 8 + j] = gates[src][j];
  }
}

// ---------- mergeA: T2t[e][lm][o] = sum_{j,k} C1o[o1,j] C2o[o2,k] dW[(j,k)][lm] ----------
__global__ __launch_bounds__(256) void k_mergeA(const float* __restrict__ W,
                                                const float* __restrict__ R,
                                                const float* __restrict__ c1o,
                                                const float* __restrict__ c2o,
                                                float* __restrict__ T2t) {
  __shared__ float dw[8 * 1024];        // [c][jk]
  __shared__ float m1[1024], m2[1024];
  int e = blockIdx.y, c0 = blockIdx.x * 8, tid = threadIdx.x;
  const float* We = W + (size_t)e * 1048576;
  for (int idx = tid; idx < 1024; idx += 256) {
    m1[idx] = c1o[e * 1024 + idx];
    m2[idx] = c2o[e * 1024 + idx];
  }
  {
    int r = tid >> 1, h = (tid & 1) * 4;
#pragma unroll
    for (int i = 0; i < 8; ++i) {
      int row = r + i * 128;
      const float4 wv = *(const float4*)(We + (size_t)row * 1024 + c0 + h);
      const float4 rv = *(const float4*)(R + (size_t)row * 1024 + c0 + h);
      dw[(h + 0) * 1024 + row] = wv.x - rv.x;
      dw[(h + 1) * 1024 + row] = wv.y - rv.y;
      dw[(h + 2) * 1024 + row] = wv.z - rv.z;
      dw[(h + 3) * 1024 + row] = wv.w - rv.w;
    }
  }
  __syncthreads();
  int i1 = tid & 31, c = tid >> 5;
  const float* dwc = dw + c * 1024;
  float U[32];
#pragma unroll
  for (int k = 0; k < 32; ++k) U[k] = 0.f;
  for (int j = 0; j < 32; ++j) {
    float cj = m1[i1 * 32 + j];
    const float4* rowp = (const float4*)(dwc + j * 32);
#pragma unroll
    for (int k4 = 0; k4 < 8; ++k4) {
      float4 v = rowp[k4];
      U[k4 * 4 + 0] += cj * v.x; U[k4 * 4 + 1] += cj * v.y;
      U[k4 * 4 + 2] += cj * v.z; U[k4 * 4 + 3] += cj * v.w;
    }
  }
  float* obase = T2t + (size_t)e * 1048576 + (size_t)(c0 + c) * 1024 + i1 * 32;
#pragma unroll
  for (int g4 = 0; g4 < 8; ++g4) {
    float s[4];
#pragma unroll
    for (int q = 0; q < 4; ++q) {
      const float4* m2r = (const float4*)(m2 + (g4 * 4 + q) * 32);
      float acc = 0.f;
#pragma unroll
      for (int k4 = 0; k4 < 8; ++k4) {
        float4 mv = m2r[k4];
        acc += mv.x * U[k4 * 4 + 0] + mv.y * U[k4 * 4 + 1]
             + mv.z * U[k4 * 4 + 2] + mv.w * U[k4 * 4 + 3];
      }
      s[q] = acc;
    }
    float4 o4; o4.x = s[0]; o4.y = s[1]; o4.z = s[2]; o4.w = s[3];
    *(float4*)(obase + g4 * 4) = o4;
  }
}

// ---------- mergeB: RW[e][o][i] = sum_{l,m} C1i[i1,l] C2i[i2,m] T2t[e][(l,m)][o] ----------
__global__ __launch_bounds__(256) void k_mergeB(const float* __restrict__ T2t,
                                                const float* __restrict__ c1i,
                                                const float* __restrict__ c2i,
                                                float* __restrict__ RW) {
  __shared__ float t2[8 * 1024];        // [oc][lm]
  __shared__ float m1[1024], m2[1024];
  int e = blockIdx.y, o0 = blockIdx.x * 8, tid = threadIdx.x;
  const float* Te = T2t + (size_t)e * 1048576;
  for (int idx = tid; idx < 1024; idx += 256) {
    m1[idx] = c1i[e * 1024 + idx];
    m2[idx] = c2i[e * 1024 + idx];
  }
  {
    int r = tid >> 1, h = (tid & 1) * 4;
#pragma unroll
    for (int i = 0; i < 8; ++i) {
      int row = r + i * 128;
      const float4 tv = *(const float4*)(Te + (size_t)row * 1024 + o0 + h);
      t2[(h + 0) * 1024 + row] = tv.x;
      t2[(h + 1) * 1024 + row] = tv.y;
      t2[(h + 2) * 1024 + row] = tv.z;
      t2[(h + 3) * 1024 + row] = tv.w;
    }
  }
  __syncthreads();
  int i1 = tid & 31, oc = tid >> 5;
  const float* t2c = t2 + oc * 1024;
  float A[32];
#pragma unroll
  for (int m = 0; m < 32; ++m) A[m] = 0.f;
  for (int l = 0; l < 32; ++l) {
    float cl = m1[i1 * 32 + l];
    const float4* rowp = (const float4*)(t2c + l * 32);
#pragma unroll
    for (int m4 = 0; m4 < 8; ++m4) {
      float4 v = rowp[m4];
      A[m4 * 4 + 0] += cl * v.x; A[m4 * 4 + 1] += cl * v.y;
      A[m4 * 4 + 2] += cl * v.z; A[m4 * 4 + 3] += cl * v.w;
    }
  }
  float* obase = RW + ((size_t)e * 1024 + o0 + oc) * 1024 + i1 * 32;
#pragma unroll
  for (int g4 = 0; g4 < 8; ++g4) {
    float s[4];
#pragma unroll
    for (int q = 0; q < 4; ++q) {
      const float4* m2r = (const float4*)(m2 + (g4 * 4 + q) * 32);
      float acc = 0.f;
#pragma unroll
      for (int m4 = 0; m4 < 8; ++m4) {
        float4 mv = m2r[m4];
        acc += mv.x * A[m4 * 4 + 0] + mv.y * A[m4 * 4 + 1]
             + mv.z * A[m4 * 4 + 2] + mv.w * A[m4 * 4 + 3];
      }
      s[q] = acc;
    }
    float4 o4; o4.x = s[0]; o4.y = s[1]; o4.z = s[2]; o4.w = s[3];
    *(float4*)(obase + g4 * 4) = o4;
  }
}

// ---------- bias curve merge ----------
__global__ __launch_bounds__(256) void k_rb(const float* __restrict__ bias,
                                            const float* __restrict__ res_bias,
                                            const float* __restrict__ c1b,
                                            const float* __restrict__ c2b,
                                            float* __restrict__ rb) {
  __shared__ float rb0[32][33], rb1[32][33], m1[32][32], m2[32][32];
  int e = blockIdx.x, tid = threadIdx.x;
  for (int idx = tid; idx < 1024; idx += 256) {
    int i = idx >> 5, j = idx & 31;
    rb0[i][j] = bias[e * 1024 + idx] - res_bias[idx];
    m1[i][j] = c1b[e * 1024 + idx];
    m2[i][j] = c2b[e * 1024 + idx];
  }
  __syncthreads();
  for (int idx = tid; idx < 1024; idx += 256) {
    int p = idx >> 5, j = idx & 31;
    float s = 0.f;
#pragma unroll
    for (int i = 0; i < 32; ++i) s += m1[p][i] * rb0[i][j];
    rb1[p][j] = s;
  }
  __syncthreads();
  for (int idx = tid; idx < 1024; idx += 256) {
    int p = idx >> 5, q = idx & 31;
    float s = 0.f;
#pragma unroll
    for (int j = 0; j < 32; ++j) s += m2[q][j] * rb1[p][j];
    rb[e * 1024 + idx] = s;
  }
}

// ---------- expert bias per chunk ----------
__global__ __launch_bounds__(256) void k_eb(const float* __restrict__ rb,
                                            const float* __restrict__ res_bias,
                                            const float* __restrict__ g,
                                            float* __restrict__ eb) {
  int b = blockIdx.x, tid = threadIdx.x;
  for (int o = tid; o < 1024; o += 256) {
    float a = res_bias[o];
#pragma unroll
    for (int e = 0; e < 8; ++e) a += g[b * 8 + e] * rb[e * 1024 + o];
    eb[b * 1024 + o] = a;
  }
}

// ---------- combine: EW[b][o][i] = bf16( R[o][i] + sum_e g[b][e] RW[e][o][i] ) ----------
__global__ __launch_bounds__(256) void k_combine(const float* __restrict__ RW,
                                                 const float* __restrict__ R,
                                                 const float* __restrict__ g,
                                                 u16* __restrict__ EW) {
  __shared__ float gs[512];
  int o = blockIdx.x, tid = threadIdx.x;
  for (int idx = tid; idx < 512; idx += 256) gs[idx] = g[idx];
  __syncthreads();
  int i0 = tid * 4;
  float4 r4 = *(const float4*)(R + (size_t)o * 1024 + i0);
  float4 w[8];
#pragma unroll
  for (int e = 0; e < 8; ++e)
    w[e] = *(const float4*)(RW + (size_t)e * 1048576 + (size_t)o * 1024 + i0);
  for (int b = 0; b < 64; ++b) {
    float a0 = r4.x, a1 = r4.y, a2 = r4.z, a3 = r4.w;
#pragma unroll
    for (int e = 0; e < 8; ++e) {
      float ge = gs[b * 8 + e];
      a0 += ge * w[e].x; a1 += ge * w[e].y; a2 += ge * w[e].z; a3 += ge * w[e].w;
    }
    u16x4 u; u.x = f2bf(a0); u.y = f2bf(a1); u.z = f2bf(a2); u.w = f2bf(a3);
    *(u16x4*)(EW + (size_t)b * 1048576 + (size_t)o * 1024 + i0) = u;
  }
}

// ---------- main GEMM: y[t][o] = sum_i x[t][i] * EW[b][o][i] + eb[b][o] ----------
__global__ __launch_bounds__(256) void k_gemm(const u16* __restrict__ Xb,
                                              const u16* __restrict__ EW,
                                              const float* __restrict__ eb,
                                              float* __restrict__ Y) {
  __shared__ alignas(16) u16 As[128 * 64];
  __shared__ alignas(16) u16 Bs[128 * 64];
  int blk = blockIdx.x;
  int nt = blk & 7, mt = (blk >> 3) & 1, b = blk >> 4;
  int t0 = b * 256 + mt * 128, o0 = nt * 128;
  int tid = threadIdx.x, lane = tid & 63, w = tid >> 6;
  int wr = w >> 1, wc = w & 1;
  f32x4 acc[4][4] = {};
  const u16* aG = Xb + (size_t)t0 * 1024;
  const u16* bG = EW + (size_t)b * 1048576 + (size_t)o0 * 1024;
  int srow = tid >> 3;
  int scol = (tid & 7) << 3;
  int gcol = (((tid & 7) ^ ((tid >> 3) & 7)) << 3);
  int lr = lane & 15;
  int sx = lr & 7;
  for (int kt = 0; kt < 16; ++kt) {
    int k0 = kt << 6;
#pragma unroll
    for (int iss = 0; iss < 4; ++iss) {
      int r = srow + iss * 32;
      ASYNC16(aG + (size_t)r * 1024 + k0 + gcol, &As[r * 64 + scol]);
    }
#pragma unroll
    for (int iss = 0; iss < 4; ++iss) {
      int r = srow + iss * 32;
      ASYNC16(bG + (size_t)r * 1024 + k0 + gcol, &Bs[r * 64 + scol]);
    }
    __syncthreads();
#pragma unroll
    for (int kk = 0; kk < 2; ++kk) {
      int c16 = kk * 4 + (lane >> 4);
      int cp = ((c16 ^ sx) << 3);
      bf16x8 af[4], bfr[4];
#pragma unroll
      for (int mi = 0; mi < 4; ++mi)
        af[mi] = *(const bf16x8*)&As[(wr * 64 + mi * 16 + lr) * 64 + cp];
#pragma unroll
      for (int ni = 0; ni < 4; ++ni)
        bfr[ni] = *(const bf16x8*)&Bs[(wc * 64 + ni * 16 + lr) * 64 + cp];
#pragma unroll
      for (int mi = 0; mi < 4; ++mi)
#pragma unroll
        for (int ni = 0; ni < 4; ++ni)
          acc[mi][ni] = __builtin_amdgcn_mfma_f32_16x16x32_bf16(af[mi], bfr[ni], acc[mi][ni], 0, 0, 0);
    }
    __syncthreads();
  }
  int rbase = (lane >> 4) << 2;
#pragma unroll
  for (int ni = 0; ni < 4; ++ni) {
    int o = o0 + wc * 64 + ni * 16 + lr;
    float ebv = eb[b * 1024 + o];
#pragma unroll
    for (int mi = 0; mi < 4; ++mi) {
      int trow = t0 + wr * 64 + mi * 16 + rbase;
      float* yp = Y + (size_t)trow * 1024 + o;
      yp[0]    = acc[mi][ni][0] + ebv;
      yp[1024] = acc[mi][ni][1] + ebv;
      yp[2048] = acc[mi][ni][2] + ebv;
      yp[3072] = acc[mi][ni][3] + ebv;
    }
  }
}

extern "C" void kernel_launch(void* const* d_in, const int* in_sizes, int n_in,
                              void* d_out, int out_size, void* d_ws, size_t ws_size,
                              hipStream_t stream) {
  const float* x      = (const float*)d_in[0];
  const float* w_gate = (const float*)d_in[1];
  const float* weight = (const float*)d_in[2];
  const float* bias   = (const float*)d_in[3];
  const float* res_w  = (const float*)d_in[4];
  const float* res_b  = (const float*)d_in[5];
  const float* c1i    = (const float*)d_in[6];
  const float* c2i    = (const float*)d_in[7];
  const float* c1o    = (const float*)d_in[8];
  const float* c2o    = (const float*)d_in[9];
  const float* c1b    = (const float*)d_in[10];
  const float* c2b    = (const float*)d_in[11];
  float* y = (float*)d_out;

  if (ws_size < WS_NEED) return;

  char* wsb = (char*)d_ws;
  u16*   xbf   = (u16*)(wsb + OFF_XBF);
  u16*   EW    = (u16*)(wsb + OFF_EW);
  float* T2t   = (float*)(wsb + OFF_T2);
  float* pm    = (float*)(wsb + OFF_PM);
  float* RW    = (float*)(wsb + OFF_RW);
  float* lgts  = (float*)(wsb + OFF_LG);
  float* g     = (float*)(wsb + OFF_G);
  float* rb    = (float*)(wsb + OFF_RB);
  float* eb    = (float*)(wsb + OFF_EB);

  k_means    <<<dim3(64, 16), 256, 0, stream>>>(x, pm, xbf);
  k_redlogits<<<64, 256, 0, stream>>>(pm, w_gate, lgts);
  k_gatefin  <<<1, 64, 0, stream>>>(lgts, g, y + 16777216);
  k_mergeA   <<<dim3(128, 8), 256, 0, stream>>>(weight, res_w, c1o, c2o, T2t);
  k_mergeB   <<<dim3(128, 8), 256, 0, stream>>>(T2t, c1i, c2i, RW);
  k_rb       <<<8, 256, 0, stream>>>(bias, res_b, c1b, c2b, rb);
  k_eb       <<<64, 256, 0, stream>>>(rb, res_b, g, eb);
  k_combine  <<<1024, 256, 0, stream>>>(RW, res_w, g, EW);
  k_gemm     <<<1024, 256, 0, stream>>>(xbf, EW, eb, y);
}

// Round 5
// 243.358 us; speedup vs baseline: 1.5655x; 1.0642x over previous
//
#include <hip/hip_runtime.h>
#include <cstdint>

typedef __bf16 bf16x8 __attribute__((ext_vector_type(8)));
typedef float  f32x4  __attribute__((ext_vector_type(4)));
using u16 = unsigned short;

struct alignas(8) u16x4 { u16 x, y, z, w; };

__device__ __forceinline__ u16 f2bf(float f) {
  unsigned u = __builtin_bit_cast(unsigned, f);
  u = (u + 0x7FFFu + ((u >> 16) & 1u)) >> 16;   // RNE; inputs finite
  return (u16)u;
}
__device__ __forceinline__ float bf2f(u16 u) {
  unsigned v = ((unsigned)u) << 16;
  return __builtin_bit_cast(float, v);
}

#define ASYNC16(gp, lp) __builtin_amdgcn_global_load_lds( \
    (__attribute__((address_space(1))) void*)(void*)(gp),  \
    (__attribute__((address_space(3))) void*)(lp), 16, 0, 0)

// ---------------- ws layout (bytes) ----------------
static constexpr size_t OFF_XBF  = 0;
static constexpr size_t OFF_EW   = 33554432;
static constexpr size_t OFF_T2   = 33554432;       // alias (mergeA -> mergeB)
static constexpr size_t OFF_PM   = 67108864;       // alias (means partials), 4 MB
static constexpr size_t OFF_RW   = 167772160;      // bf16 now (16 MB)
static constexpr size_t OFF_LG   = 201326592;      // logits [64][8]
static constexpr size_t OFF_G    = 201588736;
static constexpr size_t OFF_RB   = 201592832;
static constexpr size_t OFF_EB   = 201625600;
static constexpr size_t WS_NEED  = 201887744;

// ---------- chunk means (16-row segments) + x -> bf16 conversion ----------
__global__ __launch_bounds__(256) void k_means(const float* __restrict__ x,
                                               float* __restrict__ pm,
                                               u16* __restrict__ xbf) {
  int b = blockIdx.x, q = blockIdx.y, tid = threadIdx.x;
  const float* xb = x + (size_t)b * 262144 + (size_t)q * 16384;
  u16* xo = xbf + (size_t)b * 262144 + (size_t)q * 16384;
  float s0 = 0.f, s1 = 0.f, s2 = 0.f, s3 = 0.f;
  for (int t = 0; t < 16; ++t) {
    const float* row = xb + t * 1024;
    u16* orow = xo + t * 1024;
    float v0 = row[tid], v1 = row[tid + 256], v2 = row[tid + 512], v3 = row[tid + 768];
    s0 += v0; s1 += v1; s2 += v2; s3 += v3;
    orow[tid] = f2bf(v0); orow[tid + 256] = f2bf(v1);
    orow[tid + 512] = f2bf(v2); orow[tid + 768] = f2bf(v3);
  }
  float* p = pm + ((size_t)b * 16 + q) * 1024;
  p[tid] = s0; p[tid + 256] = s1; p[tid + 512] = s2; p[tid + 768] = s3;
}

// ---------- reduce partial means + logits GEMV (fused) ----------
__global__ __launch_bounds__(256) void k_redlogits(const float* __restrict__ pm,
                                                   const float* __restrict__ w_gate,
                                                   float* __restrict__ logits) {
  __shared__ float red[4][8];
  int b = blockIdx.x, tid = threadIdx.x;
  const float* p = pm + (size_t)b * 16384 + tid * 4;
  float4 s = {0.f, 0.f, 0.f, 0.f};
#pragma unroll
  for (int q = 0; q < 16; ++q) {
    float4 v = *(const float4*)(p + q * 1024);
    s.x += v.x; s.y += v.y; s.z += v.z; s.w += v.w;
  }
  int i0 = tid * 4;
  float acc[8];
#pragma unroll
  for (int e = 0; e < 8; ++e) {
    acc[e] = s.x * w_gate[(i0 + 0) * 8 + e] + s.y * w_gate[(i0 + 1) * 8 + e]
           + s.z * w_gate[(i0 + 2) * 8 + e] + s.w * w_gate[(i0 + 3) * 8 + e];
  }
#pragma unroll
  for (int off = 32; off >= 1; off >>= 1)
#pragma unroll
    for (int e = 0; e < 8; ++e) acc[e] += __shfl_down(acc[e], off, 64);
  int wv = tid >> 6;
  if ((tid & 63) == 0)
#pragma unroll
    for (int e = 0; e < 8; ++e) red[wv][e] = acc[e];
  __syncthreads();
  if (tid < 8)
    logits[b * 8 + tid] =
        (red[0][tid] + red[1][tid] + red[2][tid] + red[3][tid]) * (1.f / 256.f);
}

// ---------- softmax + loss + roll (tiny, 1 wave) ----------
__global__ __launch_bounds__(64) void k_gatefin(const float* __restrict__ logits,
                                                float* __restrict__ g,
                                                float* __restrict__ loss_out) {
  __shared__ float gates[64][8];
  __shared__ float imp[8];
  int b = threadIdx.x;
  {
    float lg[8];
#pragma unroll
    for (int j = 0; j < 8; ++j) lg[j] = logits[b * 8 + j];
    float mx = lg[0];
#pragma unroll
    for (int j = 1; j < 8; ++j) mx = fmaxf(mx, lg[j]);
    float s = 0.f, ex[8];
#pragma unroll
    for (int j = 0; j < 8; ++j) { ex[j] = expf(lg[j] - mx); s += ex[j]; }
    float inv = 1.f / s;
#pragma unroll
    for (int j = 0; j < 8; ++j) gates[b][j] = ex[j] * inv;
  }
  __syncthreads();
  if (b < 8) {
    float s = 0.f;
    for (int bb = 0; bb < 64; ++bb) s += gates[bb][b];
    imp[b] = s;
  }
  __syncthreads();
  if (b == 0) {
    float mean = 0.f;
#pragma unroll
    for (int j = 0; j < 8; ++j) mean += imp[j];
    mean *= (1.f / 8.f);
    float var = 0.f;
#pragma unroll
    for (int j = 0; j < 8; ++j) { float d = imp[j] - mean; var += d * d; }
    var *= (1.f / 7.f);                           // ddof=1
    loss_out[0] = (var / (mean * mean + 1e-10f)) * 1e-5f;
  }
  __syncthreads();
  {
    int src = ((b & 7) == 0) ? b : b - 1;         // roll by one chunk, keep first
#pragma unroll
    for (int j = 0; j < 8; ++j) g[b * 8 + j] = gates[src][j];
  }
}

// ---------- mergeA: T2t[e][lm][o] = sum_{j,k} C1o[o1,j] C2o[o2,k] dW[(j,k)][lm] ----------
__global__ __launch_bounds__(256) void k_mergeA(const float* __restrict__ W,
                                                const float* __restrict__ R,
                                                const float* __restrict__ c1o,
                                                const float* __restrict__ c2o,
                                                float* __restrict__ T2t) {
  __shared__ float dw[8 * 1024];        // [c][jk]
  __shared__ float m1[1024], m2[1024];
  int e = blockIdx.y, c0 = blockIdx.x * 8, tid = threadIdx.x;
  const float* We = W + (size_t)e * 1048576;
  for (int idx = tid; idx < 1024; idx += 256) {
    m1[idx] = c1o[e * 1024 + idx];
    m2[idx] = c2o[e * 1024 + idx];
  }
  {
    int r = tid >> 1, h = (tid & 1) * 4;
#pragma unroll
    for (int i = 0; i < 8; ++i) {
      int row = r + i * 128;
      const float4 wv = *(const float4*)(We + (size_t)row * 1024 + c0 + h);
      const float4 rv = *(const float4*)(R + (size_t)row * 1024 + c0 + h);
      dw[(h + 0) * 1024 + row] = wv.x - rv.x;
      dw[(h + 1) * 1024 + row] = wv.y - rv.y;
      dw[(h + 2) * 1024 + row] = wv.z - rv.z;
      dw[(h + 3) * 1024 + row] = wv.w - rv.w;
    }
  }
  __syncthreads();
  int i1 = tid & 31, c = tid >> 5;
  const float* dwc = dw + c * 1024;
  float U[32];
#pragma unroll
  for (int k = 0; k < 32; ++k) U[k] = 0.f;
  for (int j = 0; j < 32; ++j) {
    float cj = m1[i1 * 32 + j];
    const float4* rowp = (const float4*)(dwc + j * 32);
#pragma unroll
    for (int k4 = 0; k4 < 8; ++k4) {
      float4 v = rowp[k4];
      U[k4 * 4 + 0] += cj * v.x; U[k4 * 4 + 1] += cj * v.y;
      U[k4 * 4 + 2] += cj * v.z; U[k4 * 4 + 3] += cj * v.w;
    }
  }
  float* obase = T2t + (size_t)e * 1048576 + (size_t)(c0 + c) * 1024 + i1 * 32;
#pragma unroll
  for (int g4 = 0; g4 < 8; ++g4) {
    float s[4];
#pragma unroll
    for (int q = 0; q < 4; ++q) {
      const float4* m2r = (const float4*)(m2 + (g4 * 4 + q) * 32);
      float acc = 0.f;
#pragma unroll
      for (int k4 = 0; k4 < 8; ++k4) {
        float4 mv = m2r[k4];
        acc += mv.x * U[k4 * 4 + 0] + mv.y * U[k4 * 4 + 1]
             + mv.z * U[k4 * 4 + 2] + mv.w * U[k4 * 4 + 3];
      }
      s[q] = acc;
    }
    float4 o4; o4.x = s[0]; o4.y = s[1]; o4.z = s[2]; o4.w = s[3];
    *(float4*)(obase + g4 * 4) = o4;
  }
}

// ---------- mergeB: RWbf[e][o][i] = bf16( sum_{l,m} C1i[i1,l] C2i[i2,m] T2t[e][(l,m)][o] ) ----------
__global__ __launch_bounds__(256) void k_mergeB(const float* __restrict__ T2t,
                                                const float* __restrict__ c1i,
                                                const float* __restrict__ c2i,
                                                u16* __restrict__ RWbf) {
  __shared__ float t2[8 * 1024];        // [oc][lm]
  __shared__ float m1[1024], m2[1024];
  int e = blockIdx.y, o0 = blockIdx.x * 8, tid = threadIdx.x;
  const float* Te = T2t + (size_t)e * 1048576;
  for (int idx = tid; idx < 1024; idx += 256) {
    m1[idx] = c1i[e * 1024 + idx];
    m2[idx] = c2i[e * 1024 + idx];
  }
  {
    int r = tid >> 1, h = (tid & 1) * 4;
#pragma unroll
    for (int i = 0; i < 8; ++i) {
      int row = r + i * 128;
      const float4 tv = *(const float4*)(Te + (size_t)row * 1024 + o0 + h);
      t2[(h + 0) * 1024 + row] = tv.x;
      t2[(h + 1) * 1024 + row] = tv.y;
      t2[(h + 2) * 1024 + row] = tv.z;
      t2[(h + 3) * 1024 + row] = tv.w;
    }
  }
  __syncthreads();
  int i1 = tid & 31, oc = tid >> 5;
  const float* t2c = t2 + oc * 1024;
  float A[32];
#pragma unroll
  for (int m = 0; m < 32; ++m) A[m] = 0.f;
  for (int l = 0; l < 32; ++l) {
    float cl = m1[i1 * 32 + l];
    const float4* rowp = (const float4*)(t2c + l * 32);
#pragma unroll
    for (int m4 = 0; m4 < 8; ++m4) {
      float4 v = rowp[m4];
      A[m4 * 4 + 0] += cl * v.x; A[m4 * 4 + 1] += cl * v.y;
      A[m4 * 4 + 2] += cl * v.z; A[m4 * 4 + 3] += cl * v.w;
    }
  }
  u16* obase = RWbf + ((size_t)e * 1024 + o0 + oc) * 1024 + i1 * 32;
#pragma unroll
  for (int g4 = 0; g4 < 8; ++g4) {
    float s[4];
#pragma unroll
    for (int q = 0; q < 4; ++q) {
      const float4* m2r = (const float4*)(m2 + (g4 * 4 + q) * 32);
      float acc = 0.f;
#pragma unroll
      for (int m4 = 0; m4 < 8; ++m4) {
        float4 mv = m2r[m4];
        acc += mv.x * A[m4 * 4 + 0] + mv.y * A[m4 * 4 + 1]
             + mv.z * A[m4 * 4 + 2] + mv.w * A[m4 * 4 + 3];
      }
      s[q] = acc;
    }
    u16x4 o4; o4.x = f2bf(s[0]); o4.y = f2bf(s[1]); o4.z = f2bf(s[2]); o4.w = f2bf(s[3]);
    *(u16x4*)(obase + g4 * 4) = o4;
  }
}

// ---------- bias curve merge ----------
__global__ __launch_bounds__(256) void k_rb(const float* __restrict__ bias,
                                            const float* __restrict__ res_bias,
                                            const float* __restrict__ c1b,
                                            const float* __restrict__ c2b,
                                            float* __restrict__ rb) {
  __shared__ float rb0[32][33], rb1[32][33], m1[32][32], m2[32][32];
  int e = blockIdx.x, tid = threadIdx.x;
  for (int idx = tid; idx < 1024; idx += 256) {
    int i = idx >> 5, j = idx & 31;
    rb0[i][j] = bias[e * 1024 + idx] - res_bias[idx];
    m1[i][j] = c1b[e * 1024 + idx];
    m2[i][j] = c2b[e * 1024 + idx];
  }
  __syncthreads();
  for (int idx = tid; idx < 1024; idx += 256) {
    int p = idx >> 5, j = idx & 31;
    float s = 0.f;
#pragma unroll
    for (int i = 0; i < 32; ++i) s += m1[p][i] * rb0[i][j];
    rb1[p][j] = s;
  }
  __syncthreads();
  for (int idx = tid; idx < 1024; idx += 256) {
    int p = idx >> 5, q = idx & 31;
    float s = 0.f;
#pragma unroll
    for (int j = 0; j < 32; ++j) s += m2[q][j] * rb1[p][j];
    rb[e * 1024 + idx] = s;
  }
}

// ---------- expert bias per chunk ----------
__global__ __launch_bounds__(256) void k_eb(const float* __restrict__ rb,
                                            const float* __restrict__ res_bias,
                                            const float* __restrict__ g,
                                            float* __restrict__ eb) {
  int b = blockIdx.x, tid = threadIdx.x;
  for (int o = tid; o < 1024; o += 256) {
    float a = res_bias[o];
#pragma unroll
    for (int e = 0; e < 8; ++e) a += g[b * 8 + e] * rb[e * 1024 + o];
    eb[b * 1024 + o] = a;
  }
}

// ---------- combine: EW[b][o][i] = bf16( R[o][i] + sum_e g[b][e] RWbf[e][o][i] ) ----------
__global__ __launch_bounds__(256) void k_combine(const u16* __restrict__ RWbf,
                                                 const float* __restrict__ R,
                                                 const float* __restrict__ g,
                                                 u16* __restrict__ EW) {
  __shared__ float gs[512];
  int o = blockIdx.x, tid = threadIdx.x;
  for (int idx = tid; idx < 512; idx += 256) gs[idx] = g[idx];
  __syncthreads();
  int i0 = tid * 4;
  float4 r4 = *(const float4*)(R + (size_t)o * 1024 + i0);
  float4 w[8];
#pragma unroll
  for (int e = 0; e < 8; ++e) {
    u16x4 t = *(const u16x4*)(RWbf + (size_t)e * 1048576 + (size_t)o * 1024 + i0);
    w[e].x = bf2f(t.x); w[e].y = bf2f(t.y); w[e].z = bf2f(t.z); w[e].w = bf2f(t.w);
  }
  for (int b = 0; b < 64; ++b) {
    float a0 = r4.x, a1 = r4.y, a2 = r4.z, a3 = r4.w;
#pragma unroll
    for (int e = 0; e < 8; ++e) {
      float ge = gs[b * 8 + e];
      a0 += ge * w[e].x; a1 += ge * w[e].y; a2 += ge * w[e].z; a3 += ge * w[e].w;
    }
    u16x4 u; u.x = f2bf(a0); u.y = f2bf(a1); u.z = f2bf(a2); u.w = f2bf(a3);
    *(u16x4*)(EW + (size_t)b * 1048576 + (size_t)o * 1024 + i0) = u;
  }
}

// ---------- main GEMM: 256x256 tile, BK=64, 8 waves, double-buffered 2-phase ----------
// y[t][o] = sum_i x[t][i] * EW[b][o][i] + eb[b][o]
__global__ __launch_bounds__(512) void k_gemm(const u16* __restrict__ Xb,
                                              const u16* __restrict__ EW,
                                              const float* __restrict__ eb,
                                              float* __restrict__ Y) {
  __shared__ alignas(16) u16 As[2][256 * 64];
  __shared__ alignas(16) u16 Bs[2][256 * 64];
  // XCD-aware mapping: all 4 nt-blocks of a chunk land on one XCD (hw%8).
  int hw = blockIdx.x;
  int b  = (hw & 7) * 8 + (hw >> 5);
  int nt = (hw >> 3) & 3;
  int t0 = b * 256, o0 = nt * 256;
  int tid = threadIdx.x, lane = tid & 63, wv = tid >> 6;
  int wr = wv >> 2, wc = wv & 3;
  f32x4 acc[8][4] = {};
  const u16* aG = Xb + (size_t)t0 * 1024;
  const u16* bG = EW + (size_t)b * 1048576 + (size_t)o0 * 1024;
  int srow = tid >> 3;                               // 0..63
  int scol = (tid & 7) << 3;                         // linear LDS dest (rule #21)
  int gcol = (((tid & 7) ^ (srow & 7)) << 3);        // pre-swizzled global source
  int lr = lane & 15;
  int sx = lr & 7;
  // prologue: stage K-tile 0 into buf 0
#pragma unroll
  for (int iss = 0; iss < 4; ++iss) {
    int r = srow + iss * 64;
    ASYNC16(aG + (size_t)r * 1024 + gcol, &As[0][r * 64 + scol]);
    ASYNC16(bG + (size_t)r * 1024 + gcol, &Bs[0][r * 64 + scol]);
  }
  __syncthreads();
  for (int kt = 0; kt < 16; ++kt) {
    int cur = kt & 1;
    if (kt < 15) {
      int k0 = (kt + 1) << 6;
#pragma unroll
      for (int iss = 0; iss < 4; ++iss) {
        int r = srow + iss * 64;
        ASYNC16(aG + (size_t)r * 1024 + k0 + gcol, &As[cur ^ 1][r * 64 + scol]);
        ASYNC16(bG + (size_t)r * 1024 + k0 + gcol, &Bs[cur ^ 1][r * 64 + scol]);
      }
    }
#pragma unroll
    for (int kk = 0; kk < 2; ++kk) {
      int c16 = kk * 4 + (lane >> 4);
      int cp = ((c16 ^ sx) << 3);
      bf16x8 af[8], bfr[4];
#pragma unroll
      for (int mi = 0; mi < 8; ++mi)
        af[mi] = *(const bf16x8*)&As[cur][(wr * 128 + mi * 16 + lr) * 64 + cp];
#pragma unroll
      for (int ni = 0; ni < 4; ++ni)
        bfr[ni] = *(const bf16x8*)&Bs[cur][(wc * 64 + ni * 16 + lr) * 64 + cp];
#pragma unroll
      for (int mi = 0; mi < 8; ++mi)
#pragma unroll
        for (int ni = 0; ni < 4; ++ni)
          acc[mi][ni] = __builtin_amdgcn_mfma_f32_16x16x32_bf16(af[mi], bfr[ni], acc[mi][ni], 0, 0, 0);
    }
    __syncthreads();   // drains vmcnt: next tile resident; buf[cur] free for overwrite
  }
  int rbase = (lane >> 4) << 2;
#pragma unroll
  for (int ni = 0; ni < 4; ++ni) {
    int o = o0 + wc * 64 + ni * 16 + lr;
    float ebv = eb[b * 1024 + o];
#pragma unroll
    for (int mi = 0; mi < 8; ++mi) {
      int trow = t0 + wr * 128 + mi * 16 + rbase;
      float* yp = Y + (size_t)trow * 1024 + o;
      yp[0]    = acc[mi][ni][0] + ebv;
      yp[1024] = acc[mi][ni][1] + ebv;
      yp[2048] = acc[mi][ni][2] + ebv;
      yp[3072] = acc[mi][ni][3] + ebv;
    }
  }
}

extern "C" void kernel_launch(void* const* d_in, const int* in_sizes, int n_in,
                              void* d_out, int out_size, void* d_ws, size_t ws_size,
                              hipStream_t stream) {
  const float* x      = (const float*)d_in[0];
  const float* w_gate = (const float*)d_in[1];
  const float* weight = (const float*)d_in[2];
  const float* bias   = (const float*)d_in[3];
  const float* res_w  = (const float*)d_in[4];
  const float* res_b  = (const float*)d_in[5];
  const float* c1i    = (const float*)d_in[6];
  const float* c2i    = (const float*)d_in[7];
  const float* c1o    = (const float*)d_in[8];
  const float* c2o    = (const float*)d_in[9];
  const float* c1b    = (const float*)d_in[10];
  const float* c2b    = (const float*)d_in[11];
  float* y = (float*)d_out;

  if (ws_size < WS_NEED) return;

  char* wsb = (char*)d_ws;
  u16*   xbf   = (u16*)(wsb + OFF_XBF);
  u16*   EW    = (u16*)(wsb + OFF_EW);
  float* T2t   = (float*)(wsb + OFF_T2);
  float* pm    = (float*)(wsb + OFF_PM);
  u16*   RWbf  = (u16*)(wsb + OFF_RW);
  float* lgts  = (float*)(wsb + OFF_LG);
  float* g     = (float*)(wsb + OFF_G);
  float* rb    = (float*)(wsb + OFF_RB);
  float* eb    = (float*)(wsb + OFF_EB);

  k_means    <<<dim3(64, 16), 256, 0, stream>>>(x, pm, xbf);
  k_redlogits<<<64, 256, 0, stream>>>(pm, w_gate, lgts);
  k_gatefin  <<<1, 64, 0, stream>>>(lgts, g, y + 16777216);
  k_mergeA   <<<dim3(128, 8), 256, 0, stream>>>(weight, res_w, c1o, c2o, T2t);
  k_mergeB   <<<dim3(128, 8), 256, 0, stream>>>(T2t, c1i, c2i, RWbf);
  k_rb       <<<8, 256, 0, stream>>>(bias, res_b, c1b, c2b, rb);
  k_eb       <<<64, 256, 0, stream>>>(rb, res_b, g, eb);
  k_combine  <<<1024, 256, 0, stream>>>(RWbf, res_w, g, EW);
  k_gemm     <<<256, 512, 0, stream>>>(xbf, EW, eb, y);
}